// Round 4
// baseline (804.913 us; speedup 1.0000x reference)
//
#include <hip/hip_runtime.h>

typedef unsigned short u16;
typedef unsigned int u32;
typedef unsigned long long u64;

typedef __attribute__((ext_vector_type(8))) __bf16 bf16x8;
typedef __attribute__((ext_vector_type(4))) float f32x4;

// ---------- helpers ----------
__device__ __forceinline__ u16 f2bf(float f) {
  u32 u = __float_as_uint(f);
  u = (u + 0x7fffu + ((u >> 16) & 1u)) >> 16;   // RNE
  return (u16)u;
}
__device__ __forceinline__ float bf2f(u16 h) {
  return __uint_as_float(((u32)h) << 16);
}

__device__ __forceinline__ void stage16(const u16* g, u16* lds_wave_base) {
#if __has_builtin(__builtin_amdgcn_global_load_lds)
  __builtin_amdgcn_global_load_lds((__attribute__((address_space(1))) u32*)g,
                                   (__attribute__((address_space(3))) u32*)lds_wave_base,
                                   16, 0, 0);
#else
  u16* l = lds_wave_base + (threadIdx.x & 63) * 8;
  *(uint4*)l = *(const uint4*)g;
#endif
}

__device__ __forceinline__ float wred(float v) {
  v += __shfl_xor(v, 1, 64);
  v += __shfl_xor(v, 2, 64);
  v += __shfl_xor(v, 4, 64);
  v += __shfl_xor(v, 8, 64);
  v += __shfl_xor(v, 16, 64);
  v += __shfl_xor(v, 32, 64);
  return v;
}

// ---------- zero the GN stat accumulators (2048 floats) ----------
__global__ void __launch_bounds__(256) zero_stats(float* __restrict__ p) {
  int i = threadIdx.x;
#pragma unroll
  for (int j = 0; j < 8; ++j) p[j * 256 + i] = 0.f;
}

// ---------- fp32 -> bf16 elementwise (weights) ----------
__global__ void __launch_bounds__(256) f2bf_kernel(const float* __restrict__ in,
                                                   u16* __restrict__ out, int n4) {
  int i = blockIdx.x * 256 + threadIdx.x;
  if (i >= n4) return;
  float4 v = ((const float4*)in)[i];
  u64 p = (u64)f2bf(v.x) | ((u64)f2bf(v.y) << 16) | ((u64)f2bf(v.z) << 32) |
          ((u64)f2bf(v.w) << 48);
  ((u64*)out)[i] = p;
}

// ---------- transpose + convert: F[b][f][t] fp32 -> Ft[b][t][f] bf16 ----------
__global__ void __launch_bounds__(256) transpose_bf16(const float* __restrict__ src,
                                                      u16* __restrict__ dst,
                                                      long long fStride, long long oStride) {
  __shared__ float tile[64][65];
  int b = blockIdx.z;
  const float* s = src + (size_t)b * fStride;
  u16* d = dst + (size_t)b * oStride;
  int tid = threadIdx.x;
  int t0 = blockIdx.x * 64, f0 = blockIdx.y * 64;
  int r = tid >> 2, cq = (tid & 3) * 16;
#pragma unroll
  for (int q = 0; q < 4; ++q) {
    float4 v = *(const float4*)(s + (size_t)(f0 + r) * 2048 + (t0 + cq + q * 4));
    tile[r][cq + q * 4 + 0] = v.x;
    tile[r][cq + q * 4 + 1] = v.y;
    tile[r][cq + q * 4 + 2] = v.z;
    tile[r][cq + q * 4 + 3] = v.w;
  }
  __syncthreads();
  u32 ow[8];
#pragma unroll
  for (int h = 0; h < 8; ++h) {
    float lo = tile[cq + 2 * h + 0][r];
    float hi = tile[cq + 2 * h + 1][r];
    ow[h] = (u32)f2bf(lo) | ((u32)f2bf(hi) << 16);
  }
  u16* dp = d + (size_t)(t0 + r) * 2048 + f0 + cq;
  uint4 v0 = {ow[0], ow[1], ow[2], ow[3]};
  uint4 v1 = {ow[4], ow[5], ow[6], ow[7]};
  *(uint4*)dp = v0;
  *(uint4*)(dp + 8) = v1;
}

// ---------- m97-style bf16 GEMM + fused epilogue ----------
// MODE 1 (conv1): out = acc + b1[n];   GN1 group-stat atomics -> gsum.
// MODE 2 (conv2): out = mask[m]*(acc + cvec[b][n]) + b2[n]; GN2 stats -> gsum.
// A: [nb][M][K] bf16 (batch0 via A0); B: MODE1 shared [N][K], MODE2 per-batch.
template <int MODE>
__global__ void __launch_bounds__(256) gemm_bt(const u16* __restrict__ A,
                                               const u16* __restrict__ A0,
                                               const u16* __restrict__ Bw,
                                               const float* __restrict__ bias,
                                               const float* __restrict__ cvec,
                                               const float* __restrict__ masks,
                                               float* __restrict__ gsum,
                                               u16* __restrict__ Out,
                                               int M, int N, int K) {
  __shared__ u16 sA[128 * 32];
  __shared__ u16 sB[128 * 32];
  __shared__ float smask[128];
  int tid = threadIdx.x;
  int bz = blockIdx.z;
  int m0 = blockIdx.x * 128, n0 = blockIdx.y * 128;
  const u16* Ab = (bz == 0) ? A0 : (A + (size_t)bz * M * K);
  const u16* Bb = (MODE == 2) ? (Bw + (size_t)bz * N * K) : Bw;
  int lane = tid & 63, wid = tid >> 6;
  int wm = wid >> 1, wn = wid & 1;
  int lm = lane >> 4, ln = lane & 15;
  int ldr = tid >> 2, lko = (tid & 3) * 8;
  const u16* ga = Ab + (size_t)(m0 + ldr) * K + lko;
  const u16* gb = Bb + (size_t)(n0 + ldr) * K + lko;
  size_t rs64 = (size_t)64 * K;
  u16* aL1 = &sA[wid * 512];
  u16* aL2 = aL1 + 2048;
  u16* bL1 = &sB[wid * 512];
  u16* bL2 = bL1 + 2048;

  if (MODE == 2 && tid < 128) smask[tid] = masks[(size_t)bz * 2048 + m0 + tid];

  f32x4 acc[4][4];
#pragma unroll
  for (int mi = 0; mi < 4; ++mi)
#pragma unroll
    for (int ni = 0; ni < 4; ++ni)
      acc[mi][ni] = (f32x4){0.f, 0.f, 0.f, 0.f};

  int ncolv[4];
  float biasv[4], cvecv[4];
#pragma unroll
  for (int ni = 0; ni < 4; ++ni) {
    ncolv[ni] = n0 + wn * 64 + ni * 16 + ln;
    biasv[ni] = bias[ncolv[ni]];
    cvecv[ni] = (MODE == 2) ? cvec[(size_t)bz * 512 + ncolv[ni]] : 0.f;
  }

  int nk = K >> 5;
  for (int kt = 0; kt < nk; ++kt) {
    int k0 = kt << 5;
    __syncthreads();
    stage16(ga + k0, aL1);
    stage16(ga + rs64 + k0, aL2);
    stage16(gb + k0, bL1);
    stage16(gb + rs64 + k0, bL2);
    __syncthreads();
    bf16x8 af[4], bfv[4];
#pragma unroll
    for (int mi = 0; mi < 4; ++mi)
      af[mi] = *(const bf16x8*)&sA[(wm * 64 + mi * 16 + ln) * 32 + lm * 8];
#pragma unroll
    for (int ni = 0; ni < 4; ++ni)
      bfv[ni] = *(const bf16x8*)&sB[(wn * 64 + ni * 16 + ln) * 32 + lm * 8];
#pragma unroll
    for (int mi = 0; mi < 4; ++mi)
#pragma unroll
      for (int ni = 0; ni < 4; ++ni)
        acc[mi][ni] =
            __builtin_amdgcn_mfma_f32_16x16x32_bf16(af[mi], bfv[ni], acc[mi][ni], 0, 0, 0);
  }

  // epilogue: write + per-group stats. C/D: col=lane&15, row=(lane>>4)*4+reg
  u16* ob = Out + (size_t)bz * M * N;
  float sg[4] = {0.f, 0.f, 0.f, 0.f}, ssg[4] = {0.f, 0.f, 0.f, 0.f};
#pragma unroll
  for (int mi = 0; mi < 4; ++mi) {
    int lrow = wm * 64 + mi * 16 + lm * 4;
#pragma unroll
    for (int ni = 0; ni < 4; ++ni) {
#pragma unroll
      for (int r = 0; r < 4; ++r) {
        float v = acc[mi][ni][r];
        if (MODE == 1) {
          v = v + biasv[ni];
        } else {
          v = smask[lrow + r] * (v + cvecv[ni]) + biasv[ni];
        }
        ob[(size_t)(m0 + lrow + r) * N + ncolv[ni]] = f2bf(v);
        sg[ni] += v;
        ssg[ni] += v * v;
      }
    }
  }
#pragma unroll
  for (int ni = 0; ni < 4; ++ni) {
    float s = wred(sg[ni]);
    float ss = wred(ssg[ni]);
    if (lane == 0) {
      int g = (n0 >> 4) + wn * 4 + ni;   // global group 0..31
      float* gp = gsum + ((size_t)bz * 32 + g) * 2;
      atomicAdd(gp, s);
      atomicAdd(gp + 1, ss);
    }
  }
}

// ---------- finalize GN stats: gm[b][ch], ad[b][ch] from group sums ----------
__global__ void __launch_bounds__(256) gn_finalize(const float* __restrict__ gsum,
                                                   const float* __restrict__ gamma,
                                                   const float* __restrict__ beta,
                                                   float* __restrict__ gm,
                                                   float* __restrict__ ad) {
  int idx = blockIdx.x * 256 + threadIdx.x;   // 8192 = 16 b x 512 ch
  int b = idx >> 9, ch = idx & 511;
  int g = ch >> 4;
  float s = gsum[((size_t)b * 32 + g) * 2];
  float ss = gsum[((size_t)b * 32 + g) * 2 + 1];
  const float cnt = 16.f * 2048.f;
  float mu = s / cnt;
  float var = ss / cnt - mu * mu;
  float inv = rsqrtf(var + 1e-5f);
  float gmv = gamma[ch] * inv;
  gm[idx] = gmv;
  ad[idx] = beta[ch] - mu * gmv;
}

// ---------- fold: W2p[b][o][k] = bf16( W2[o][k] * gm1[b][k] ) ----------
__global__ void __launch_bounds__(256) fold_w2(const float* __restrict__ W2,
                                               const float* __restrict__ gm1,
                                               u16* __restrict__ W2p) {
  size_t flat = ((size_t)blockIdx.x * 256 + threadIdx.x) * 4;  // over 16*512*512
  int b = (int)(flat >> 18);
  int rem = (int)(flat & 262143);
  int o = rem >> 9, k = rem & 511;
  float4 wv = *(const float4*)(W2 + (size_t)o * 512 + k);
  float4 gv = *(const float4*)(gm1 + (size_t)b * 512 + k);
  u64 p = (u64)f2bf(wv.x * gv.x) | ((u64)f2bf(wv.y * gv.y) << 16) |
          ((u64)f2bf(wv.z * gv.z) << 32) | ((u64)f2bf(wv.w * gv.w) << 48);
  *(u64*)(W2p + flat) = p;
}

// ---------- cvec[b][o] = sum_k W2[o][k] * ad1[b][k] ----------
__global__ void __launch_bounds__(256) cvec_kernel(const float* __restrict__ W2,
                                                   const float* __restrict__ ad1,
                                                   float* __restrict__ cvec) {
  int tid = threadIdx.x;
  int wid = tid >> 6, lane = tid & 63;
  int o = blockIdx.x * 4 + wid;      // grid.x = 128
  int b = blockIdx.y;                // 16
  int k0 = lane * 8;
  const float* wr = W2 + (size_t)o * 512 + k0;
  const float* ar = ad1 + (size_t)b * 512 + k0;
  float s = 0.f;
#pragma unroll
  for (int j = 0; j < 8; ++j) s += wr[j] * ar[j];
  s = wred(s);
  if (lane == 0) cvec[(size_t)b * 512 + o] = s;
}

// ---------- heads: Out[b][c][t] = (CLS: sigmoid(mk*dot + bc), else dot) ----------
template <typename TX, bool CLS>
__global__ void __launch_bounds__(512) head_v2(const TX* __restrict__ X,
                                               const float* __restrict__ W,
                                               const float* __restrict__ bcv,
                                               const float* __restrict__ gma,
                                               const float* __restrict__ gad,
                                               const float* __restrict__ masks,
                                               float* __restrict__ Out, int Tdim) {
  __shared__ float red[64 * 20];
  int tid = threadIdx.x;
  int tl = tid & 63;
  int ks = __builtin_amdgcn_readfirstlane(tid >> 6);   // 0..7, wave-uniform
  int b = blockIdx.y;
  int t = blockIdx.x * 64 + tl;
  for (int i = tid; i < 64 * 20; i += 512) red[i] = 0.f;
  float acc[20];
#pragma unroll
  for (int c = 0; c < 20; ++c) acc[c] = 0.f;
  const TX* xr = X + ((size_t)b * Tdim + t) * 512 + ks * 64;
  const float* Wk = W + ks * 64;
  const float* gmk = CLS ? (gma + (size_t)b * 512 + ks * 64) : nullptr;
  const float* gak = CLS ? (gad + (size_t)b * 512 + ks * 64) : nullptr;
  __syncthreads();
#pragma unroll
  for (int kk = 0; kk < 64; kk += 8) {
    float xv[8];
    if constexpr (sizeof(TX) == 2) {
      uint4 v = *(const uint4*)(xr + kk);
      u32 wv[4] = {v.x, v.y, v.z, v.w};
#pragma unroll
      for (int h = 0; h < 4; ++h) {
        xv[2 * h] = bf2f((u16)(wv[h] & 0xffffu));
        xv[2 * h + 1] = bf2f((u16)(wv[h] >> 16));
      }
    } else {
      float4 p0 = *(const float4*)(xr + kk);
      float4 p1 = *(const float4*)(xr + kk + 4);
      xv[0] = p0.x; xv[1] = p0.y; xv[2] = p0.z; xv[3] = p0.w;
      xv[4] = p1.x; xv[5] = p1.y; xv[6] = p1.z; xv[7] = p1.w;
    }
    if constexpr (CLS) {
#pragma unroll
      for (int j = 0; j < 8; ++j) xv[j] = xv[j] * gmk[kk + j] + gak[kk + j];
    }
#pragma unroll
    for (int c = 0; c < 20; ++c) {
      const float* wr = &Wk[c * 512 + kk];
#pragma unroll
      for (int j = 0; j < 8; ++j) acc[c] += xv[j] * wr[j];
    }
  }
#pragma unroll
  for (int c = 0; c < 20; ++c) atomicAdd(&red[tl * 20 + c], acc[c]);
  __syncthreads();
  if (tid < 64) {
    float mk = CLS ? masks[(size_t)b * Tdim + t] : 1.f;
#pragma unroll
    for (int c = 0; c < 20; ++c) {
      float v = red[tid * 20 + c];
      if constexpr (CLS) {
        v = v * mk + bcv[c];
        v = 1.f / (1.f + __expf(-v));
      }
      Out[((size_t)b * 20 + c) * Tdim + t] = v;
    }
  }
}

// ---------- top-k mean: bitonic sort 2048 in LDS ----------
__global__ void __launch_bounds__(256) topk_kernel(const float* __restrict__ textL,
                                                   const float* __restrict__ clsL,
                                                   const float* __restrict__ img_masks,
                                                   const float* __restrict__ masks,
                                                   float* __restrict__ out) {
  __shared__ float d[2048];
  __shared__ float rbuf[4];
  int bx = blockIdx.x;
  int head = bx / 320, rem = bx - head * 320;
  int b = rem / 20, c = rem - b * 20;
  int tid = threadIdx.x;
  const float* mk = head ? (masks + (size_t)b * 2048) : (img_masks + (size_t)b * 2048);
  float ls = 0.f;
  for (int i = tid; i < 2048; i += 256) ls += mk[i];
  ls = wred(ls);
  if ((tid & 63) == 0) rbuf[tid >> 6] = ls;
  const float* rowp = (head ? clsL : textL) + ((size_t)(b * 20 + c)) * 2048;
  for (int i = tid; i < 2048; i += 256) d[i] = rowp[i];
  __syncthreads();
  int len = (int)(rbuf[0] + rbuf[1] + rbuf[2] + rbuf[3]);
  int k = len >> 3;
  if (k < 1) k = 1;
  for (int size = 2; size <= 2048; size <<= 1) {
    for (int stride = size >> 1; stride > 0; stride >>= 1) {
      __syncthreads();
      for (int i = tid; i < 2048; i += 256) {
        int j = i ^ stride;
        if (j > i) {
          float a = d[i], bb = d[j];
          bool desc = ((i & size) == 0);
          if (desc ? (a < bb) : (a > bb)) { d[i] = bb; d[j] = a; }
        }
      }
    }
  }
  __syncthreads();
  float ps = 0.f;
  for (int i = tid; i < k; i += 256) ps += d[i];
  ps = wred(ps);
  __syncthreads();
  if ((tid & 63) == 0) rbuf[tid >> 6] = ps;
  __syncthreads();
  if (tid == 0) out[bx] = (rbuf[0] + rbuf[1] + rbuf[2] + rbuf[3]) / (float)k;
}

// ---------- host ----------
extern "C" void kernel_launch(void* const* d_in, const int* in_sizes, int n_in,
                              void* d_out, int out_size, void* d_ws, size_t ws_size,
                              hipStream_t stream) {
  const float* F          = (const float*)d_in[0];   // [16,2048,2048]
  const float* masks      = (const float*)d_in[1];   // [16,1,2048]
  const float* text_proto = (const float*)d_in[2];   // [1,20,512]
  const float* img_feats  = (const float*)d_in[3];   // [16,2048,512]
  const float* img_masks  = (const float*)d_in[4];   // [16,2048]
  const float* W1 = (const float*)d_in[5];
  const float* b1 = (const float*)d_in[6];
  const float* g1 = (const float*)d_in[7];
  const float* be1 = (const float*)d_in[8];
  const float* W2 = (const float*)d_in[9];
  const float* b2 = (const float*)d_in[10];
  const float* g2 = (const float*)d_in[11];
  const float* be2 = (const float*)d_in[12];
  const float* Wc = (const float*)d_in[13];
  const float* bc = (const float*)d_in[14];
  float* out = (float*)d_out;

  const int T = 2048, Fd = 2048, O = 512;
  char* w = (char*)d_ws;
  // carve (bytes):
  u16* W1b     = (u16*)(w);                    // 2 MB
  u16* x1      = (u16*)(w + 2097152);          // 33.5 MB
  float* clsL  = (float*)(w + 35651584);       // 2.62 MB
  float* textL = (float*)(w + 38273024);       // 2.62 MB
  float* gma   = (float*)(w + 40894464);       // 32 KB
  float* gad   = (float*)(w + 40927232);       // 32 KB
  float* gm1   = (float*)(w + 40960000);       // 32 KB
  float* ad1   = (float*)(w + 40992768);       // 32 KB
  float* cvec  = (float*)(w + 41025536);       // 32 KB
  float* gn1s  = (float*)(w + 41058304);       // 4 KB
  float* gn2s  = (float*)(w + 41062400);       // 4 KB
  u16* W2p     = (u16*)(w + 41066496);         // 8.39 MB
  const size_t oEnd0 = 49455104;
  const size_t ftBytes = (size_t)16 * T * Fd * 2;   // 134,217,728

  zero_stats<<<1, 256, 0, stream>>>(gn1s);     // zeros gn1s+gn2s (contiguous 8 KB)
  f2bf_kernel<<<1024, 256, 0, stream>>>(W1, W1b, (O * Fd) / 4);

  const u16 *FtA, *FtA0;
  u16* x2;
  if (ws_size >= oEnd0 + ftBytes) {
    u16* Ft = (u16*)(w + oEnd0);
    transpose_bf16<<<dim3(32, 32, 16), 256, 0, stream>>>(F, Ft, (long long)Fd * T,
                                                         (long long)T * Fd);
    FtA = Ft; FtA0 = Ft; x2 = Ft;   // x2 aliases Ft (dead after GEMM1)
  } else {
    u16* ft0 = (u16*)(w + oEnd0);
    x2 = (u16*)(w + oEnd0 + (size_t)T * Fd * 2);
    for (int b = 0; b < 16; ++b) {
      u16* dst = (b == 0) ? ft0 : ((u16*)d_in[0]) + (size_t)b * T * Fd;
      transpose_bf16<<<dim3(32, 32, 1), 256, 0, stream>>>(F + (size_t)b * Fd * T, dst, 0, 0);
    }
    FtA = (const u16*)d_in[0]; FtA0 = ft0;
  }

  // conv1 + GN1 stats
  gemm_bt<1><<<dim3(16, 4, 16), 256, 0, stream>>>(FtA, FtA0, W1b, b1, nullptr, nullptr,
                                                  gn1s, x1, 2048, 512, 2048);
  gn_finalize<<<32, 256, 0, stream>>>(gn1s, g1, be1, gm1, ad1);
  fold_w2<<<4096, 256, 0, stream>>>(W2, gm1, W2p);
  cvec_kernel<<<dim3(128, 16), 256, 0, stream>>>(W2, ad1, cvec);
  // conv2 (GN1 folded in) + GN2 stats
  gemm_bt<2><<<dim3(16, 4, 16), 256, 0, stream>>>(x1, x1, W2p, b2, cvec, masks,
                                                  gn2s, x2, 2048, 512, 512);
  gn_finalize<<<32, 256, 0, stream>>>(gn2s, g2, be2, gma, gad);
  // heads (GN2 affine + mask fused into cls head)
  head_v2<u16, true><<<dim3(32, 16), 512, 0, stream>>>(x2, Wc, bc, gma, gad, masks, clsL, 2048);
  head_v2<float, false><<<dim3(32, 16), 512, 0, stream>>>(img_feats, text_proto, nullptr,
                                                          nullptr, nullptr, nullptr, textL, 2048);
  topk_kernel<<<640, 256, 0, stream>>>(textL, clsL, img_masks, masks, out);
}